// Round 4
// baseline (426.510 us; speedup 1.0000x reference)
//
#include <hip/hip_runtime.h>
#include <hip/hip_bf16.h>

typedef unsigned short u16;
typedef __attribute__((ext_vector_type(8))) short bf16x8;          // 8 bf16 = 4 VGPRs
typedef __attribute__((ext_vector_type(8))) unsigned short u16x8;  // 16B of bf16
typedef __attribute__((ext_vector_type(4))) float f32x4;

#define EPSN 1e-9f

// ---------- helpers ----------

__device__ __forceinline__ u16 f2bf(float f) {
    union { float f; unsigned int u; } c; c.f = f;
    unsigned int u = c.u;
    unsigned int r = (u + 0x7FFFu + ((u >> 16) & 1u)) >> 16;   // RNE
    return (u16)r;
}

__device__ __forceinline__ float bf2f(u16 b) {
    union { unsigned int u; float f; } c; c.u = ((unsigned int)b) << 16;
    return c.f;
}

__device__ __forceinline__ void load16_to_lds(const void* g, void* l) {
    __builtin_amdgcn_global_load_lds(
        (const __attribute__((address_space(1))) void*)g,
        (__attribute__((address_space(3))) void*)l,
        16, 0, 0);
}

// ---------- K1: per-row L2 normalize + cast to bf16, one WAVE per row ----------
// No LDS, no barriers. Row data (<=2048 cols) held in registers between passes.
// Optionally zero-fills rowzero[row] (saves a separate memset dispatch).
__global__ __launch_bounds__(256) void normalize_cast_rows(
    const float* __restrict__ X, u16* __restrict__ Y,
    float* __restrict__ rowzero, int ncols, int nrows) {
    const int row  = blockIdx.x * 4 + (threadIdx.x >> 6);
    if (row >= nrows) return;
    const int lane = threadIdx.x & 63;
    const float4* xr = (const float4*)(X + (size_t)row * ncols);
    const int nq = ncols >> 2;   // ncols multiple of 4, <= 2048

    float4 v[8];
    float ss = 0.f;
    #pragma unroll
    for (int k = 0; k < 8; ++k) {
        int i = lane + (k << 6);
        if (i < nq) {
            v[k] = xr[i];
            ss += v[k].x*v[k].x + v[k].y*v[k].y + v[k].z*v[k].z + v[k].w*v[k].w;
        }
    }
    #pragma unroll
    for (int o = 32; o > 0; o >>= 1) ss += __shfl_xor(ss, o);
    const float s = 1.f / (sqrtf(ss) + EPSN);

    if (rowzero && lane == 0) rowzero[row] = 0.f;

    ushort4* yr = (ushort4*)(Y + (size_t)row * ncols);
    #pragma unroll
    for (int k = 0; k < 8; ++k) {
        int i = lane + (k << 6);
        if (i < nq) {
            ushort4 o4;
            o4.x = f2bf(v[k].x * s); o4.y = f2bf(v[k].y * s);
            o4.z = f2bf(v[k].z * s); o4.w = f2bf(v[k].w * s);
            yr[i] = o4;
        }
    }
}

// ---------- K2: bf16 MFMA GEMM (A[M,K] * B[N,K]^T) + fused relu/pow epilogue ----------
// 128x128 tile, BK=64, 4 waves each computing 64x64 via 4x4 grid of 16x16x32 MFMA.
// LDS XOR-swizzle: chunk (row, kc) of 8 bf16 stored at position kc ^ (row&7)
// -> global_load_lds stays contiguous (base + lane*16), ds_read_b128 is 2-way max.
// __launch_bounds__(256,2): caps VGPR at ~60 -> 40% occupancy (R2: 254->158us win).
// Epilogue computes exp(logprior) inline and stores u either as bf16 (workspace
// path, halves write+re-read traffic) or f32 (fallback straight to d_out).
#define BK 64

template <bool BF16OUT>
__global__ __launch_bounds__(256, 2) void gemm_softhebb(
    const u16* __restrict__ A, const u16* __restrict__ B,
    const float* __restrict__ logprior, const float* __restrict__ lambp,
    void* __restrict__ Uout, float* __restrict__ rowsum,
    int M, int N, int K) {
    __shared__ __align__(16) u16 lA[128 * BK];
    __shared__ __align__(16) u16 lB[128 * BK];

    const int tid  = threadIdx.x;
    const int lane = tid & 63;
    const int wm   = (tid >> 6) & 1;   // wave row (0..1)
    const int wn   = tid >> 7;         // wave col (0..1)
    const int row0 = blockIdx.y * 128;
    const int col0 = blockIdx.x * 128;

    f32x4 acc[4][4] = {};

    // staging indices: chunk c = p*256+tid; row=c>>3, stored pos=c&7,
    // global kchunk = (c&7) ^ (row&7)
    const u16* ap[4];
    const u16* bp[4];
    #pragma unroll
    for (int p = 0; p < 4; ++p) {
        int c = p * 256 + tid;
        int r = c >> 3;
        int o = ((c & 7) ^ (r & 7)) * 8;
        ap[p] = A + (size_t)(row0 + r) * K + o;
        bp[p] = B + (size_t)(col0 + r) * K + o;
    }

    for (int k0 = 0; k0 < K; k0 += BK) {
        #pragma unroll
        for (int p = 0; p < 4; ++p) {
            int c = p * 256 + tid;
            load16_to_lds(ap[p] + k0, &lA[c * 8]);
            load16_to_lds(bp[p] + k0, &lB[c * 8]);
        }
        __syncthreads();

        #pragma unroll
        for (int s = 0; s < 2; ++s) {
            // fragment row r has (r&7)==(lane&7); kchunk = s*4 + (lane>>4)
            const int pos = (((s << 2) + (lane >> 4)) ^ (lane & 7)) * 8;
            bf16x8 af[4], bfr[4];
            #pragma unroll
            for (int i = 0; i < 4; ++i) {
                int r = wm * 64 + i * 16 + (lane & 15);
                af[i] = *(const bf16x8*)&lA[r * 64 + pos];
            }
            #pragma unroll
            for (int j = 0; j < 4; ++j) {
                int r = wn * 64 + j * 16 + (lane & 15);
                bfr[j] = *(const bf16x8*)&lB[r * 64 + pos];
            }
            #pragma unroll
            for (int i = 0; i < 4; ++i)
                #pragma unroll
                for (int j = 0; j < 4; ++j)
                    acc[i][j] = __builtin_amdgcn_mfma_f32_16x16x32_bf16(
                        af[i], bfr[j], acc[i][j], 0, 0, 0);
        }
        __syncthreads();
    }

    // epilogue: u = relu(a); ul = u^lam * exp(logprior); store + row partial sums
    // C/D layout: col = lane&15, row = (lane>>4)*4 + p   [m89/m91 verified]
    const float lam = *lambp;
    const bool lam4 = (lam == 4.0f);
    float el[4];
    #pragma unroll
    for (int j = 0; j < 4; ++j)
        el[j] = expf(logprior[col0 + wn * 64 + j * 16 + (lane & 15)]);

    #pragma unroll
    for (int i = 0; i < 4; ++i) {
        #pragma unroll
        for (int p = 0; p < 4; ++p) {
            const int m = row0 + wm * 64 + i * 16 + (lane >> 4) * 4 + p;
            const size_t base = (size_t)m * N + col0 + wn * 64 + (lane & 15);
            float rs = 0.f;
            #pragma unroll
            for (int j = 0; j < 4; ++j) {
                float a = acc[i][j][p];
                float u = 0.f;
                if (a > 0.f) {
                    float pw;
                    if (lam4) { float a2 = a * a; pw = a2 * a2; }
                    else      { pw = __powf(a, lam); }
                    u = pw * el[j];
                }
                if (BF16OUT) {
                    u16 r = f2bf(u);
                    ((u16*)Uout)[base + j * 16] = r;
                    rs += bf2f(r);            // sum the rounded value for consistency
                } else {
                    ((float*)Uout)[base + j * 16] = u;
                    rs += u;
                }
            }
            // reduce across the 16 lanes sharing this row (lanes differ in low 4 bits)
            rs += __shfl_xor(rs, 1);
            rs += __shfl_xor(rs, 2);
            rs += __shfl_xor(rs, 4);
            rs += __shfl_xor(rs, 8);
            if ((lane & 15) == 0) atomicAdd(&rowsum[m], rs);
        }
    }
}

// ---------- K3a: y = u_bf16 / (rowsum + eps), one wave per row, NT stores ----------
__global__ __launch_bounds__(256) void finalize_rows_bf16(
    const u16* __restrict__ U, const float* __restrict__ rowsum,
    float* __restrict__ Y, int ncols) {
    const int row  = blockIdx.x * 4 + (threadIdx.x >> 6);
    const int lane = threadIdx.x & 63;
    const float inv = 1.f / (rowsum[row] + EPSN);
    const u16x8* ur = (const u16x8*)(U + (size_t)row * ncols);
    float* yr = Y + (size_t)row * ncols;
    const int n8 = ncols >> 3;
    for (int i = lane; i < n8; i += 64) {
        u16x8 u8 = ur[i];
        f32x4 lo, hi;
        lo[0] = bf2f(u8[0]) * inv; lo[1] = bf2f(u8[1]) * inv;
        lo[2] = bf2f(u8[2]) * inv; lo[3] = bf2f(u8[3]) * inv;
        hi[0] = bf2f(u8[4]) * inv; hi[1] = bf2f(u8[5]) * inv;
        hi[2] = bf2f(u8[6]) * inv; hi[3] = bf2f(u8[7]) * inv;
        __builtin_nontemporal_store(lo, (f32x4*)(yr + i * 8));
        __builtin_nontemporal_store(hi, (f32x4*)(yr + i * 8 + 4));
    }
}

// ---------- K3b fallback: in-place f32 divide, one block per row ----------
__global__ __launch_bounds__(256) void finalize_row_f32(
    float* __restrict__ Ul, const float* __restrict__ rowsum, int nq) {
    const size_t row = blockIdx.x;
    const float inv = 1.f / (rowsum[row] + EPSN);
    float4* p = (float4*)(Ul + row * (size_t)nq * 4);
    for (int i = threadIdx.x; i < nq; i += 256) {
        float4 v = p[i];
        v.x *= inv; v.y *= inv; v.z *= inv; v.w *= inv;
        p[i] = v;
    }
}

// ---------- launch ----------
static inline size_t align256(size_t x) { return (x + 255) & ~(size_t)255; }

extern "C" void kernel_launch(void* const* d_in, const int* in_sizes, int n_in,
                              void* d_out, int out_size, void* d_ws, size_t ws_size,
                              hipStream_t stream) {
    const float* x        = (const float*)d_in[0];
    const float* w        = (const float*)d_in[1];
    const float* logprior = (const float*)d_in[2];
    const float* lamb     = (const float*)d_in[3];
    const int OUT = in_sizes[2];                // 2048
    const int IN  = in_sizes[1] / OUT;          // 2048
    const int B   = in_sizes[0] / IN;           // 16384
    float* out = (float*)d_out;

    char* ws = (char*)d_ws;
    size_t off = 0;
    u16* xn = (u16*)(ws + off);         off += align256((size_t)B * IN * sizeof(u16));
    u16* wn = (u16*)(ws + off);         off += align256((size_t)OUT * IN * sizeof(u16));
    float* rowsum = (float*)(ws + off); off += align256((size_t)B * sizeof(float));
    u16* ub = (u16*)(ws + off);         off += align256((size_t)B * OUT * sizeof(u16));
    const bool bf16path = (off <= ws_size);

    normalize_cast_rows<<<(B + 3) / 4, 256, 0, stream>>>(x, xn, rowsum, IN, B);
    normalize_cast_rows<<<(OUT + 3) / 4, 256, 0, stream>>>(w, wn, nullptr, IN, OUT);

    dim3 grid(OUT / 128, B / 128);
    if (bf16path) {
        gemm_softhebb<true><<<grid, 256, 0, stream>>>(
            xn, wn, logprior, lamb, (void*)ub, rowsum, B, OUT, IN);
        finalize_rows_bf16<<<B / 4, 256, 0, stream>>>(ub, rowsum, out, OUT);
    } else {
        gemm_softhebb<false><<<grid, 256, 0, stream>>>(
            xn, wn, logprior, lamb, (void*)out, rowsum, B, OUT, IN);
        finalize_row_f32<<<B, 256, 0, stream>>>(out, rowsum, OUT / 4);
    }
}

// Round 5
// 423.286 us; speedup vs baseline: 1.0076x; 1.0076x over previous
//
#include <hip/hip_runtime.h>
#include <hip/hip_bf16.h>

typedef unsigned short u16;
typedef __attribute__((ext_vector_type(8))) short bf16x8;          // 8 bf16 = 4 VGPRs
typedef __attribute__((ext_vector_type(8))) unsigned short u16x8;  // 16B of bf16
typedef __attribute__((ext_vector_type(4))) float f32x4;

#define EPSN 1e-9f

// ---------- helpers ----------

__device__ __forceinline__ u16 f2bf(float f) {
    union { float f; unsigned int u; } c; c.f = f;
    unsigned int u = c.u;
    unsigned int r = (u + 0x7FFFu + ((u >> 16) & 1u)) >> 16;   // RNE
    return (u16)r;
}

__device__ __forceinline__ float bf2f(u16 b) {
    union { unsigned int u; float f; } c; c.u = ((unsigned int)b) << 16;
    return c.f;
}

__device__ __forceinline__ void load16_to_lds(const void* g, void* l) {
    __builtin_amdgcn_global_load_lds(
        (const __attribute__((address_space(1))) void*)g,
        (__attribute__((address_space(3))) void*)l,
        16, 0, 0);
}

// ---------- K1: per-row L2 normalize + cast to bf16, one WAVE per row ----------
// Handles BOTH x and w in one dispatch (rows [0,nx) -> x, rows [nx,ntot) -> w).
// No LDS, no barriers. Row data (<=2048 cols) held in registers between passes.
// Also zero-fills rowzero[row] for x rows (saves a separate memset dispatch).
__global__ __launch_bounds__(256) void normalize_cast_rows(
    const float* __restrict__ X, u16* __restrict__ Xn,
    const float* __restrict__ W, u16* __restrict__ Wn,
    float* __restrict__ rowzero, int ncols, int nx, int ntot) {
    const int row  = blockIdx.x * 4 + (threadIdx.x >> 6);
    if (row >= ntot) return;
    const int lane = threadIdx.x & 63;
    const float* src;
    u16* dst;
    if (row < nx) { src = X + (size_t)row * ncols;        dst = Xn + (size_t)row * ncols; }
    else          { src = W + (size_t)(row - nx) * ncols; dst = Wn + (size_t)(row - nx) * ncols; }
    const float4* xr = (const float4*)src;
    const int nq = ncols >> 2;   // ncols multiple of 4, <= 2048

    float4 v[8];
    float ss = 0.f;
    #pragma unroll
    for (int k = 0; k < 8; ++k) {
        int i = lane + (k << 6);
        if (i < nq) {
            v[k] = xr[i];
            ss += v[k].x*v[k].x + v[k].y*v[k].y + v[k].z*v[k].z + v[k].w*v[k].w;
        }
    }
    #pragma unroll
    for (int o = 32; o > 0; o >>= 1) ss += __shfl_xor(ss, o);
    const float s = 1.f / (sqrtf(ss) + EPSN);

    if (row < nx && lane == 0) rowzero[row] = 0.f;

    ushort4* yr = (ushort4*)dst;
    #pragma unroll
    for (int k = 0; k < 8; ++k) {
        int i = lane + (k << 6);
        if (i < nq) {
            ushort4 o4;
            o4.x = f2bf(v[k].x * s); o4.y = f2bf(v[k].y * s);
            o4.z = f2bf(v[k].z * s); o4.w = f2bf(v[k].w * s);
            yr[i] = o4;
        }
    }
}

// ---------- K2: bf16 MFMA GEMM (A[M,K] * B[N,K]^T) + fused relu/pow epilogue ----------
// 128x128 tile, BK=64, 4 waves each computing 64x64 via 4x4 grid of 16x16x32 MFMA.
// LDS XOR-swizzle: chunk (row, kc) of 8 bf16 stored at position kc ^ (row&7)
// -> global_load_lds stays contiguous (base + lane*16), ds_read_b128 is 2-way max.
// __launch_bounds__(256,2): caps VGPR at ~60 -> 40% occupancy (R2: 254->158us win).
// XCD swizzle (R5): all 16 col-blocks of a row-stripe get linear ids == g (mod 8)
// -> same XCD (round-robin dispatch heuristic) and consecutive there -> A-stripe
// (512 KB) stays L2-resident across its 16 consumers; B (8 MB) serves from L3.
#define BK 64

template <bool BF16OUT>
__global__ __launch_bounds__(256, 2) void gemm_softhebb(
    const u16* __restrict__ A, const u16* __restrict__ B,
    const float* __restrict__ logprior, const float* __restrict__ lambp,
    void* __restrict__ Uout, float* __restrict__ rowsum,
    int M, int N, int K) {
    __shared__ __align__(16) u16 lA[128 * BK];
    __shared__ __align__(16) u16 lB[128 * BK];

    const int tid  = threadIdx.x;
    const int lane = tid & 63;
    const int wm   = (tid >> 6) & 1;   // wave row (0..1)
    const int wn   = tid >> 7;         // wave col (0..1)

    // XCD-aware remap: lid -> (xb, yb) with all xb of a stripe on one XCD
    const int gx  = gridDim.x;                       // N/128 col-blocks
    const int lid = blockIdx.y * gx + blockIdx.x;
    const int g   = lid & 7;
    const int t   = lid >> 3;
    const int xb  = t % gx;
    const int yb  = g + ((t / gx) << 3);
    const int row0 = yb * 128;
    const int col0 = xb * 128;

    f32x4 acc[4][4] = {};

    // staging indices: chunk c = p*256+tid; row=c>>3, stored pos=c&7,
    // global kchunk = (c&7) ^ (row&7)
    const u16* ap[4];
    const u16* bp[4];
    #pragma unroll
    for (int p = 0; p < 4; ++p) {
        int c = p * 256 + tid;
        int r = c >> 3;
        int o = ((c & 7) ^ (r & 7)) * 8;
        ap[p] = A + (size_t)(row0 + r) * K + o;
        bp[p] = B + (size_t)(col0 + r) * K + o;
    }

    for (int k0 = 0; k0 < K; k0 += BK) {
        #pragma unroll
        for (int p = 0; p < 4; ++p) {
            int c = p * 256 + tid;
            load16_to_lds(ap[p] + k0, &lA[c * 8]);
            load16_to_lds(bp[p] + k0, &lB[c * 8]);
        }
        __syncthreads();

        #pragma unroll
        for (int s = 0; s < 2; ++s) {
            // fragment row r has (r&7)==(lane&7); kchunk = s*4 + (lane>>4)
            const int pos = (((s << 2) + (lane >> 4)) ^ (lane & 7)) * 8;
            bf16x8 af[4], bfr[4];
            #pragma unroll
            for (int i = 0; i < 4; ++i) {
                int r = wm * 64 + i * 16 + (lane & 15);
                af[i] = *(const bf16x8*)&lA[r * 64 + pos];
            }
            #pragma unroll
            for (int j = 0; j < 4; ++j) {
                int r = wn * 64 + j * 16 + (lane & 15);
                bfr[j] = *(const bf16x8*)&lB[r * 64 + pos];
            }
            #pragma unroll
            for (int i = 0; i < 4; ++i)
                #pragma unroll
                for (int j = 0; j < 4; ++j)
                    acc[i][j] = __builtin_amdgcn_mfma_f32_16x16x32_bf16(
                        af[i], bfr[j], acc[i][j], 0, 0, 0);
        }
        __syncthreads();
    }

    // epilogue: u = relu(a); ul = u^lam * exp(logprior); store + row partial sums
    // C/D layout: col = lane&15, row = (lane>>4)*4 + p   [m89/m91 verified]
    const float lam = *lambp;
    const bool lam4 = (lam == 4.0f);
    float el[4];
    #pragma unroll
    for (int j = 0; j < 4; ++j)
        el[j] = expf(logprior[col0 + wn * 64 + j * 16 + (lane & 15)]);

    #pragma unroll
    for (int i = 0; i < 4; ++i) {
        #pragma unroll
        for (int p = 0; p < 4; ++p) {
            const int m = row0 + wm * 64 + i * 16 + (lane >> 4) * 4 + p;
            const size_t base = (size_t)m * N + col0 + wn * 64 + (lane & 15);
            float rs = 0.f;
            #pragma unroll
            for (int j = 0; j < 4; ++j) {
                float a = acc[i][j][p];
                float u = 0.f;
                if (a > 0.f) {
                    float pw;
                    if (lam4) { float a2 = a * a; pw = a2 * a2; }
                    else      { pw = __powf(a, lam); }
                    u = pw * el[j];
                }
                if (BF16OUT) {
                    u16 r = f2bf(u);
                    ((u16*)Uout)[base + j * 16] = r;
                    rs += bf2f(r);            // sum the rounded value for consistency
                } else {
                    ((float*)Uout)[base + j * 16] = u;
                    rs += u;
                }
            }
            // reduce across the 16 lanes sharing this row (lanes differ in low 4 bits)
            rs += __shfl_xor(rs, 1);
            rs += __shfl_xor(rs, 2);
            rs += __shfl_xor(rs, 4);
            rs += __shfl_xor(rs, 8);
            if ((lane & 15) == 0) atomicAdd(&rowsum[m], rs);
        }
    }
}

// ---------- K3a: y = u_bf16 / (rowsum + eps), one wave per row, NT stores ----------
__global__ __launch_bounds__(256) void finalize_rows_bf16(
    const u16* __restrict__ U, const float* __restrict__ rowsum,
    float* __restrict__ Y, int ncols) {
    const int row  = blockIdx.x * 4 + (threadIdx.x >> 6);
    const int lane = threadIdx.x & 63;
    const float inv = 1.f / (rowsum[row] + EPSN);
    const u16x8* ur = (const u16x8*)(U + (size_t)row * ncols);
    float* yr = Y + (size_t)row * ncols;
    const int n8 = ncols >> 3;
    for (int i = lane; i < n8; i += 64) {
        u16x8 u8 = ur[i];
        f32x4 lo, hi;
        lo[0] = bf2f(u8[0]) * inv; lo[1] = bf2f(u8[1]) * inv;
        lo[2] = bf2f(u8[2]) * inv; lo[3] = bf2f(u8[3]) * inv;
        hi[0] = bf2f(u8[4]) * inv; hi[1] = bf2f(u8[5]) * inv;
        hi[2] = bf2f(u8[6]) * inv; hi[3] = bf2f(u8[7]) * inv;
        __builtin_nontemporal_store(lo, (f32x4*)(yr + i * 8));
        __builtin_nontemporal_store(hi, (f32x4*)(yr + i * 8 + 4));
    }
}

// ---------- K3b fallback: in-place f32 divide, one block per row ----------
__global__ __launch_bounds__(256) void finalize_row_f32(
    float* __restrict__ Ul, const float* __restrict__ rowsum, int nq) {
    const size_t row = blockIdx.x;
    const float inv = 1.f / (rowsum[row] + EPSN);
    float4* p = (float4*)(Ul + row * (size_t)nq * 4);
    for (int i = threadIdx.x; i < nq; i += 256) {
        float4 v = p[i];
        v.x *= inv; v.y *= inv; v.z *= inv; v.w *= inv;
        p[i] = v;
    }
}

// ---------- launch ----------
static inline size_t align256(size_t x) { return (x + 255) & ~(size_t)255; }

extern "C" void kernel_launch(void* const* d_in, const int* in_sizes, int n_in,
                              void* d_out, int out_size, void* d_ws, size_t ws_size,
                              hipStream_t stream) {
    const float* x        = (const float*)d_in[0];
    const float* w        = (const float*)d_in[1];
    const float* logprior = (const float*)d_in[2];
    const float* lamb     = (const float*)d_in[3];
    const int OUT = in_sizes[2];                // 2048
    const int IN  = in_sizes[1] / OUT;          // 2048
    const int B   = in_sizes[0] / IN;           // 16384
    float* out = (float*)d_out;

    char* ws = (char*)d_ws;
    size_t off = 0;
    u16* xn = (u16*)(ws + off);         off += align256((size_t)B * IN * sizeof(u16));
    u16* wn = (u16*)(ws + off);         off += align256((size_t)OUT * IN * sizeof(u16));
    float* rowsum = (float*)(ws + off); off += align256((size_t)B * sizeof(float));
    u16* ub = (u16*)(ws + off);         off += align256((size_t)B * OUT * sizeof(u16));
    const bool bf16path = (off <= ws_size);

    const int ntot = B + OUT;
    normalize_cast_rows<<<(ntot + 3) / 4, 256, 0, stream>>>(
        x, xn, w, wn, rowsum, IN, B, ntot);

    dim3 grid(OUT / 128, B / 128);
    if (bf16path) {
        gemm_softhebb<true><<<grid, 256, 0, stream>>>(
            xn, wn, logprior, lamb, (void*)ub, rowsum, B, OUT, IN);
        finalize_rows_bf16<<<B / 4, 256, 0, stream>>>(ub, rowsum, out, OUT);
    } else {
        gemm_softhebb<false><<<grid, 256, 0, stream>>>(
            xn, wn, logprior, lamb, (void*)out, rowsum, B, OUT, IN);
        finalize_row_f32<<<B, 256, 0, stream>>>(out, rowsum, OUT / 4);
    }
}